// Round 9
// baseline (953.040 us; speedup 1.0000x reference)
//
#include <hip/hip_runtime.h>
#include <stdint.h>
#include <stddef.h>

#define H_DIM 512
#define M_DIM 4096
#define TOPK  64
#define BAND_CAP 128
#define DEC_CAP 96
#define NBINS 2048

typedef __attribute__((ext_vector_type(8))) short bf16x8;
typedef __attribute__((ext_vector_type(4))) float floatx4;
typedef __attribute__((ext_vector_type(8))) unsigned short ushort8;

static __device__ __forceinline__ unsigned short f2bf(float f) {
    union { float ff; unsigned int i; } v; v.ff = f;
    unsigned int u = v.i;
    u += 0x7FFFu + ((u >> 16) & 1u);   // RNE
    return (unsigned short)(u >> 16);
}

static __device__ __forceinline__ float bfl(unsigned int u) { return __uint_as_float(u << 16); }
static __device__ __forceinline__ float bfh(unsigned int u) { return __uint_as_float(u & 0xFFFF0000u); }

static __device__ __forceinline__ void gload16(const void* g, void* l) {
    __builtin_amdgcn_global_load_lds(
        (const __attribute__((address_space(1))) unsigned int*)g,
        (__attribute__((address_space(3))) unsigned int*)l, 16, 0, 0);
}

// np-exact fp32 logit: single sequential FMA chain k=0..511 + bias + relu
static __device__ __forceinline__ float np_chain(const float* __restrict__ Enc,
                                                 const float* __restrict__ benc,
                                                 const float* xs, int m) {
    const float* er = Enc + (size_t)m * H_DIM;
    float s = 0.f;
#pragma unroll 8
    for (int k = 0; k < H_DIM; ++k) s = fmaf(xs[k], er[k], s);
    float lg = s + benc[m];
    return lg > 0.f ? lg : 0.f;
}

// ---- prep: Xbf[n*H+h] = bf16(X - bpre)
__global__ void sae_conv_x(const float* __restrict__ X, const float* __restrict__ bpre,
                           unsigned short* __restrict__ Xbf) {
    int g = (blockIdx.x * 256 + threadIdx.x) * 8;
    int h = g & (H_DIM - 1);
    float4 a0 = *(const float4*)(X + g);
    float4 a1 = *(const float4*)(X + g + 4);
    float4 p0 = *(const float4*)(bpre + h);
    float4 p1 = *(const float4*)(bpre + h + 4);
    ushort8 o;
    o[0] = f2bf(a0.x - p0.x); o[1] = f2bf(a0.y - p0.y);
    o[2] = f2bf(a0.z - p0.z); o[3] = f2bf(a0.w - p0.w);
    o[4] = f2bf(a1.x - p1.x); o[5] = f2bf(a1.y - p1.y);
    o[6] = f2bf(a1.z - p1.z); o[7] = f2bf(a1.w - p1.w);
    *(ushort8*)(Xbf + g) = o;
}

// ---- prep: Encbf = bf16(Enc)
__global__ void sae_conv_enc(const float* __restrict__ Enc, unsigned short* __restrict__ Eb) {
    int g = (blockIdx.x * 256 + threadIdx.x) * 8;
    float4 b0 = *(const float4*)(Enc + g);
    float4 b1 = *(const float4*)(Enc + g + 4);
    ushort8 o;
    o[0] = f2bf(b0.x); o[1] = f2bf(b0.y); o[2] = f2bf(b0.z); o[3] = f2bf(b0.w);
    o[4] = f2bf(b1.x); o[5] = f2bf(b1.y); o[6] = f2bf(b1.z); o[7] = f2bf(b1.w);
    *(ushort8*)(Eb + g) = o;
}

// ---- prep: decTb[m*H + h] = bf16(dec[h*M + m])
__global__ void sae_conv_decT(const float* __restrict__ dec, unsigned short* __restrict__ decTb) {
    __shared__ float tile[64][65];
    const int m0 = blockIdx.x * 64;
    const int h0 = blockIdx.y * 64;
    const int tid = threadIdx.x;
#pragma unroll
    for (int it = 0; it < 16; ++it) {
        int r = it * 4 + (tid >> 6);
        int c = tid & 63;
        tile[r][c] = dec[(size_t)(h0 + r) * M_DIM + m0 + c];
    }
    __syncthreads();
    const int ml = tid >> 2;
    const int q  = tid & 3;
    ushort8 o0, o1;
#pragma unroll
    for (int e = 0; e < 8; ++e) o0[e] = f2bf(tile[q * 16 + e][ml]);
#pragma unroll
    for (int e = 0; e < 8; ++e) o1[e] = f2bf(tile[q * 16 + 8 + e][ml]);
    unsigned short* out = decTb + (size_t)(m0 + ml) * H_DIM + h0 + q * 16;
    *(ushort8*)(out)     = o0;
    *(ushort8*)(out + 8) = o1;
}

// ---- K1 fast path: 128x128 BK=64. XCD swizzle m-OUTER/n-INNER: per XCD only
// one 128KB Encbf panel must stay L2-resident (A streams). Epilogue stores are
// NONTEMPORAL so the z-write stream doesn't evict the panel.
__launch_bounds__(256, 4)
__global__ void sae_encode_gemm64(const unsigned short* __restrict__ Xbf,   // [N,H] bf16
                                  const unsigned short* __restrict__ Encbf, // [M,H] bf16
                                  const float* __restrict__ benc,
                                  unsigned short* __restrict__ zb)
{
    __shared__ unsigned short lA[128 * 64];   // 16 KB
    __shared__ unsigned short lB[128 * 64];   // 16 KB
    const int tid  = threadIdx.x;
    const int lane = tid & 63;
    const int wave = tid >> 6;
    const int wx = wave & 1, wy = wave >> 1;

    // bijective XCD swizzle: XCD k owns swz [k*512,(k+1)*512) = m-tiles
    // [4k,4k+4), n inner. Consecutive co-launched blocks share one B panel.
    const int bid = blockIdx.x;                     // 0..4095
    const int swz = (bid & 7) * 512 + (bid >> 3);
    const int mBase = (swz >> 7) * 128;             // m outer (B panel hot)
    const int nBase = (swz & 127) * 128;            // n inner (A streams)

    floatx4 acc[4][4];
#pragma unroll
    for (int i = 0; i < 4; ++i)
#pragma unroll
        for (int j = 0; j < 4; ++j) acc[i][j] = (floatx4){0.f, 0.f, 0.f, 0.f};

    const int gRow = wave * 32 + (lane >> 3);
    const int gCol = (lane & 7) * 8;
    const int lOff = wave * 2048 + lane * 8;
    const unsigned short* gA = Xbf  + (size_t)(nBase + gRow) * H_DIM + gCol;
    const unsigned short* gB = Encbf + (size_t)(mBase + gRow) * H_DIM + gCol;

    const int quad = lane >> 4;
    const int l15  = lane & 15;

    for (int kt = 0; kt < H_DIM / 64; ++kt) {
        const int k0 = kt * 64;
        __syncthreads();
#pragma unroll
        for (int j = 0; j < 4; ++j)
            gload16(gA + (size_t)(j * 8) * H_DIM + k0, &lA[lOff + j * 512]);
#pragma unroll
        for (int j = 0; j < 4; ++j)
            gload16(gB + (size_t)(j * 8) * H_DIM + k0, &lB[lOff + j * 512]);
        __syncthreads();
#pragma unroll
        for (int kk = 0; kk < 2; ++kk) {
            bf16x8 af[4], bfr[4];
#pragma unroll
            for (int i = 0; i < 4; ++i)
                af[i] = *(const bf16x8*)&lA[(wy * 64 + i * 16 + l15) * 64 + kk * 32 + quad * 8];
#pragma unroll
            for (int j = 0; j < 4; ++j)
                bfr[j] = *(const bf16x8*)&lB[(wx * 64 + j * 16 + l15) * 64 + kk * 32 + quad * 8];
#pragma unroll
            for (int i = 0; i < 4; ++i)
#pragma unroll
                for (int j = 0; j < 4; ++j)
                    acc[i][j] = __builtin_amdgcn_mfma_f32_16x16x32_bf16(af[i], bfr[j], acc[i][j], 0, 0, 0);
        }
    }

#pragma unroll
    for (int i = 0; i < 4; ++i) {
        int nLoc = nBase + wy * 64 + i * 16 + quad * 4;
#pragma unroll
        for (int j = 0; j < 4; ++j) {
            int m = mBase + wx * 64 + j * 16 + l15;
            float bc = benc[m];
#pragma unroll
            for (int r = 0; r < 4; ++r) {
                float v = acc[i][j][r] + bc;
                v = v > 0.f ? v : 0.f;
                __builtin_nontemporal_store((unsigned short)f2bf(v),
                                            &zb[(size_t)(nLoc + r) * (M_DIM * 2) + m]);
            }
        }
    }
}

// ---- K1 fallback (small ws): BK=32 128x128 kernel with inline f2bf, bf16 epilogue
template<int BBF>
__launch_bounds__(256, 2)
__global__ void sae_encode_gemm(const float* __restrict__ X,
                                const float* __restrict__ Enc,
                                const unsigned short* __restrict__ Encbf,
                                const float* __restrict__ bpre,
                                const float* __restrict__ benc,
                                unsigned short* __restrict__ zb)
{
    __shared__ unsigned short lA[128 * 32];
    __shared__ unsigned short lB[128 * 32];
    const int tid  = threadIdx.x;
    const int lane = tid & 63;
    const int wave = tid >> 6;
    const int wx = wave & 1, wy = wave >> 1;
    const int mBase = blockIdx.x * 128;
    const int nBase = blockIdx.y * 128;

    floatx4 acc[4][4];
#pragma unroll
    for (int i = 0; i < 4; ++i)
#pragma unroll
        for (int j = 0; j < 4; ++j) acc[i][j] = (floatx4){0.f, 0.f, 0.f, 0.f};

    const int sRow = tid >> 1;
    const int sCol = (tid & 1) * 16;
    const size_t aRow = (size_t)(nBase + sRow) * H_DIM;
    const size_t bRow = (size_t)(mBase + sRow) * H_DIM;
    unsigned short* sA = &lA[sRow * 32 + sCol];
    unsigned short* sB = &lB[sRow * 32 + sCol];

    const int gR0 = wave * 32 + (lane >> 2);
    const int gR1 = gR0 + 16;
    const int gC  = (lane & 3) * 8;
    const int lOff0 = wave * 1024 + lane * 8;
    const int lOff1 = lOff0 + 512;

    const int quad = lane >> 4;
    const int l15  = lane & 15;

    for (int kt = 0; kt < H_DIM / 32; ++kt) {
        const int k0 = kt * 32;
        ushort8 wa0, wa1, wb0, wb1;
#pragma unroll
        for (int c = 0; c < 2; ++c) {
            float4 a0 = *(const float4*)(X + aRow + k0 + sCol + c * 8);
            float4 a1 = *(const float4*)(X + aRow + k0 + sCol + c * 8 + 4);
            float4 p0 = *(const float4*)(bpre + k0 + sCol + c * 8);
            float4 p1 = *(const float4*)(bpre + k0 + sCol + c * 8 + 4);
            ushort8 wa;
            wa[0] = f2bf(a0.x - p0.x); wa[1] = f2bf(a0.y - p0.y);
            wa[2] = f2bf(a0.z - p0.z); wa[3] = f2bf(a0.w - p0.w);
            wa[4] = f2bf(a1.x - p1.x); wa[5] = f2bf(a1.y - p1.y);
            wa[6] = f2bf(a1.z - p1.z); wa[7] = f2bf(a1.w - p1.w);
            if (c == 0) wa0 = wa; else wa1 = wa;
        }
        if constexpr (!BBF) {
#pragma unroll
            for (int c = 0; c < 2; ++c) {
                float4 b0 = *(const float4*)(Enc + bRow + k0 + sCol + c * 8);
                float4 b1 = *(const float4*)(Enc + bRow + k0 + sCol + c * 8 + 4);
                ushort8 wb;
                wb[0] = f2bf(b0.x); wb[1] = f2bf(b0.y); wb[2] = f2bf(b0.z); wb[3] = f2bf(b0.w);
                wb[4] = f2bf(b1.x); wb[5] = f2bf(b1.y); wb[6] = f2bf(b1.z); wb[7] = f2bf(b1.w);
                if (c == 0) wb0 = wb; else wb1 = wb;
            }
        }
        __syncthreads();
        *(ushort8*)(sA)     = wa0;
        *(ushort8*)(sA + 8) = wa1;
        if constexpr (!BBF) {
            *(ushort8*)(sB)     = wb0;
            *(ushort8*)(sB + 8) = wb1;
        } else {
            gload16(Encbf + (size_t)(mBase + gR0) * H_DIM + k0 + gC, &lB[lOff0]);
            gload16(Encbf + (size_t)(mBase + gR1) * H_DIM + k0 + gC, &lB[lOff1]);
        }
        __syncthreads();
        bf16x8 af[4], bfr[4];
#pragma unroll
        for (int i = 0; i < 4; ++i)
            af[i] = *(const bf16x8*)&lA[(wy * 64 + i * 16 + l15) * 32 + quad * 8];
#pragma unroll
        for (int j = 0; j < 4; ++j)
            bfr[j] = *(const bf16x8*)&lB[(wx * 64 + j * 16 + l15) * 32 + quad * 8];
#pragma unroll
        for (int i = 0; i < 4; ++i)
#pragma unroll
            for (int j = 0; j < 4; ++j)
                acc[i][j] = __builtin_amdgcn_mfma_f32_16x16x32_bf16(af[i], bfr[j], acc[i][j], 0, 0, 0);
    }

#pragma unroll
    for (int i = 0; i < 4; ++i) {
        int nLoc = nBase + wy * 64 + i * 16 + quad * 4;
#pragma unroll
        for (int j = 0; j < 4; ++j) {
            int m = mBase + wx * 64 + j * 16 + l15;
            float bc = benc[m];
#pragma unroll
            for (int r = 0; r < 4; ++r) {
                float v = acc[i][j][r] + bc;
                v = v > 0.f ? v : 0.f;
                zb[(size_t)(nLoc + r) * (M_DIM * 2) + m] = f2bf(v);
            }
        }
    }
}

// fused decode: x_tgt row from the kc keeps in LDS, bf16 decT gathers
static __device__ __forceinline__ void sae_row_decode(
    const unsigned short* __restrict__ decTb,
    const int* kIdx, const float* kVal, int kc,
    int row, int tid, float p0, float p1,
    float* __restrict__ xOut)
{
    float a0 = 0.f, a1 = 0.f;
    for (int j = 0; j < kc; ++j) {
        float v = kVal[j];
        int m = kIdx[j];
        unsigned int d = *(const unsigned int*)(decTb + (size_t)m * H_DIM + tid * 2);
        a0 = fmaf(v, bfl(d), a0);
        a1 = fmaf(v, bfh(d), a1);
    }
    float2 o; o.x = a0 + p0; o.y = a1 + p1;
    *(float2*)(xOut + (size_t)row * H_DIM + tid * 2) = o;
}

// ---- K2: exact top-64 from bf16 intermediate.
// Band ranking: sequential np-exact fp32 chains (selection-critical, ~15-40).
// Definite-keep values: wave-cooperative dots from L2-RESIDENT bf16 Encbf
// (value-only, MFMA-class accuracy), concurrent with the chains.
// Bulk zero-write NONTEMPORAL so decTb/Encbf stay resident for the gathers.
__launch_bounds__(256, 2)
__global__ void sae_topk(float* __restrict__ zbase,
                         const float* __restrict__ X,
                         const float* __restrict__ Enc,
                         const float* __restrict__ bpre,
                         const float* __restrict__ benc,
                         const unsigned short* __restrict__ decTb,
                         const unsigned short* __restrict__ Encb,   // bf16, may be null
                         float* __restrict__ xOut,
                         int doDec)
{
    const unsigned short* zb = (const unsigned short*)zbase;
    __shared__ unsigned int hist[NBINS];      // 8 KB
    __shared__ unsigned int wsum[4];
    __shared__ unsigned int scanb[256];
    __shared__ float xs[H_DIM];
    __shared__ int   bandIdx[BAND_CAP];
    __shared__ float bandVal[BAND_CAP];
    __shared__ int   defIdx[TOPK];
    __shared__ int   kIdx[TOPK];
    __shared__ float kVal[TOPK];
    __shared__ int   sBand, sDef, sKeep, sBin, sAbove;

    const int tid  = threadIdx.x;
    const int lane = tid & 63;
    const int wave = tid >> 6;
    const int row  = blockIdx.x;

    // coalesced bf16 row load: elem m(i) = (i>>3)*2048 + tid*8 + (i&7)
    unsigned int u[16];
    float val[16];
    {
        const ushort8* srcb = (const ushort8*)(zb + (size_t)row * (M_DIM * 2));
        ushort8 w0 = srcb[tid];
        ushort8 w1 = srcb[256 + tid];
#pragma unroll
        for (int e = 0; e < 8; ++e) {
            u[e]     = ((unsigned int)(unsigned short)w0[e]) << 16;
            u[8 + e] = ((unsigned int)(unsigned short)w1[e]) << 16;
        }
#pragma unroll
        for (int i = 0; i < 16; ++i) val[i] = __uint_as_float(u[i]);
    }
#define ZIDX(i) (((i) >> 3) * 2048 + tid * 8 + ((i) & 7))

    // early-issue the X row
    float x0 = X[(size_t)row * H_DIM + tid * 2];
    float x1 = X[(size_t)row * H_DIM + tid * 2 + 1];
    float p0 = bpre[tid * 2], p1 = bpre[tid * 2 + 1];

    if (tid == 0) { sBand = 0; sDef = 0; sKeep = 0; sBin = -1; }
#pragma unroll
    for (int i = 0; i < NBINS / 256; ++i) hist[tid + i * 256] = 0u;
    __syncthreads();
#pragma unroll
    for (int i = 0; i < 16; ++i)
        if (u[i]) atomicAdd(&hist[u[i] >> 20], 1u);
    __syncthreads();

    // level-1 suffix scan
    unsigned int h8[8];
    {
        const int base = tid * 8;
        unsigned int s = 0;
#pragma unroll
        for (int i = 0; i < 8; ++i) { h8[i] = hist[base + i]; s += h8[i]; }
        unsigned int suf = s;
#pragma unroll
        for (int off = 1; off < 64; off <<= 1) {
            unsigned int o = __shfl_down(suf, off);
            if (lane + off < 64) suf += o;
        }
        if (lane == 0) wsum[wave] = suf;
        __syncthreads();
        unsigned int hiW = 0;
        for (int w = wave + 1; w < 4; ++w) hiW += wsum[w];
        suf += hiW;
        if (suf >= (unsigned)TOPK && suf - s < (unsigned)TOPK) {
            unsigned int above = suf - s;
#pragma unroll
            for (int i = 7; i >= 0; --i) {
                if (above + h8[i] >= (unsigned)TOPK) { sBin = base + i; sAbove = (int)above; break; }
                above += h8[i];
            }
        }
        __syncthreads();
    }
    const unsigned int total = wsum[0] + wsum[1] + wsum[2] + wsum[3];

    if (total < (unsigned)TOPK) {
        // fewer than 64 positives: keep all, values np-exact (rare path)
        floatx4 z4 = (floatx4){0.f, 0.f, 0.f, 0.f};
        floatx4* dst = (floatx4*)(zbase + (size_t)row * M_DIM);
#pragma unroll
        for (int c = 0; c < 4; ++c) dst[c * 256 + tid] = z4;
        xs[tid * 2]     = x0 - p0;
        xs[tid * 2 + 1] = x1 - p1;
#pragma unroll
        for (int i = 0; i < 16; ++i)
            if (u[i]) {
                int p = atomicAdd(&sKeep, 1);
                if (p < TOPK) kIdx[p] = ZIDX(i);
            }
        __syncthreads();
        int kc = sKeep; if (kc > TOPK) kc = TOPK;
        if (tid < kc) kVal[tid] = np_chain(Enc, benc, xs, kIdx[tid]);
        __syncthreads();
        if (tid < kc) zbase[(size_t)row * M_DIM + kIdx[tid]] = kVal[tid];
        if (doDec) sae_row_decode(decTb, kIdx, kVal, kc, row, tid, p0, p1, xOut);
        return;
    }

    const int b1 = sBin;
    const unsigned int above1 = (unsigned int)sAbove;
    __syncthreads();

    // level-2: bits 19..9 (bf16 values quantized -> bracket is exact)
#pragma unroll
    for (int i = 0; i < NBINS / 256; ++i) hist[tid + i * 256] = 0u;
    if (tid == 0) sBin = -1;
    __syncthreads();
#pragma unroll
    for (int i = 0; i < 16; ++i)
        if (u[i] && (int)(u[i] >> 20) == b1) atomicAdd(&hist[(u[i] >> 9) & 0x7FFu], 1u);
    __syncthreads();
    const unsigned int Kneed = (unsigned)TOPK - above1;
    {
        const int base = tid * 8;
        unsigned int s = 0;
#pragma unroll
        for (int i = 0; i < 8; ++i) { h8[i] = hist[base + i]; s += h8[i]; }
        unsigned int suf = s;
#pragma unroll
        for (int off = 1; off < 64; off <<= 1) {
            unsigned int o = __shfl_down(suf, off);
            if (lane + off < 64) suf += o;
        }
        if (lane == 0) wsum[wave] = suf;
        __syncthreads();
        unsigned int hiW = 0;
        for (int w = wave + 1; w < 4; ++w) hiW += wsum[w];
        suf += hiW;
        if (suf >= Kneed && suf - s < Kneed) {
            unsigned int above = suf - s;
#pragma unroll
            for (int i = 7; i >= 0; --i) {
                if (above + h8[i] >= Kneed) { sBin = base + i; break; }
                above += h8[i];
            }
        }
        __syncthreads();
    }
    const unsigned int T = ((unsigned int)b1 << 20) | ((unsigned int)sBin << 9);
    const float Tf  = __uint_as_float(T);
    const float Tub = __uint_as_float(T + (1u << 9));

    // margin: MFMA-vs-np (~0.04+0.01T) + bf16 storage rounding (0.39%)
    const float marg = 0.045f + 0.015f * Tub;
    float lo = Tf - marg; if (lo <= 0.f) lo = 1e-12f;
    const float hi = Tub + marg;

    // collect definite keeps (> hi) and band candidates [lo, hi]; stage xs
#pragma unroll
    for (int i = 0; i < 16; ++i) {
        float v = val[i];
        if (v > hi) {
            int p = atomicAdd(&sDef, 1);
            if (p < TOPK) defIdx[p] = ZIDX(i);
        } else if (v >= lo) {
            int p = atomicAdd(&sBand, 1);
            if (p < BAND_CAP) bandIdx[p] = ZIDX(i);
        }
    }
    xs[tid * 2]     = x0 - p0;
    xs[tid * 2 + 1] = x1 - p1;
    __syncthreads();
    int nDef = sDef; if (nDef > TOPK) nDef = TOPK;   // mathematically <= 63
    const int Bn = sBand;

    if (Bn > BAND_CAP) {
        // pathological fallback: radix-select on bf16 stored values, np-exact keeps
        floatx4 z4 = (floatx4){0.f, 0.f, 0.f, 0.f};
        floatx4* dst = (floatx4*)(zbase + (size_t)row * M_DIM);
#pragma unroll
        for (int c = 0; c < 4; ++c) dst[c * 256 + tid] = z4;
        if (tid == 0) sKeep = 0;

        unsigned int uold[16];
        {
            const ushort8* so = (const ushort8*)(zb + (size_t)row * (M_DIM * 2)) + tid * 2;
            ushort8 a = so[0], b = so[1];
#pragma unroll
            for (int e = 0; e < 8; ++e) {
                uold[e]     = ((unsigned int)(unsigned short)a[e]) << 16;
                uold[8 + e] = ((unsigned int)(unsigned short)b[e]) << 16;
            }
        }
        unsigned int Tx = 0;
        for (int bit = 30; bit >= 16; --bit) {   // low 16 bits always 0 for bf16
            unsigned int cand = Tx | (1u << bit);
            int c = 0;
#pragma unroll
            for (int i = 0; i < 16; ++i) c += (uold[i] >= cand) ? 1 : 0;
            for (int off = 32; off >= 1; off >>= 1) c += __shfl_down(c, off);
            __syncthreads();
            if (lane == 0) wsum[wave] = (unsigned int)c;
            __syncthreads();
            if (wsum[0] + wsum[1] + wsum[2] + wsum[3] >= TOPK) Tx = cand;
        }
        int c = 0;
#pragma unroll
        for (int i = 0; i < 16; ++i) c += (uold[i] > Tx) ? 1 : 0;
        for (int off = 32; off >= 1; off >>= 1) c += __shfl_down(c, off);
        __syncthreads();
        if (lane == 0) wsum[wave] = (unsigned int)c;
        __syncthreads();
        unsigned int q = TOPK - (wsum[0] + wsum[1] + wsum[2] + wsum[3]);
        unsigned int myT = 0;
#pragma unroll
        for (int i = 0; i < 16; ++i) myT += (uold[i] == Tx) ? 1u : 0u;
        scanb[tid] = myT;
        __syncthreads();
        if (tid == 0) {
            unsigned int run = 0;
            for (int t = 0; t < 256; ++t) { unsigned int c2 = scanb[t]; scanb[t] = run; run += c2; }
        }
        __syncthreads();
        unsigned int tieRank = scanb[tid];
#pragma unroll
        for (int i = 0; i < 16; ++i) {
            bool isTie = (uold[i] == Tx);
            bool keep  = (uold[i] > Tx) || (isTie && tieRank < q);
            if (isTie) tieRank++;
            if (keep) {
                int p = atomicAdd(&sKeep, 1);
                if (p < TOPK) kIdx[p] = tid * 16 + i;
            }
        }
        __syncthreads();
        int kc = sKeep; if (kc > TOPK) kc = TOPK;
        if (tid < kc) kVal[tid] = np_chain(Enc, benc, xs, kIdx[tid]);
        __syncthreads();
        if (tid < kc) zbase[(size_t)row * M_DIM + kIdx[tid]] = kVal[tid];
        if (doDec) sae_row_decode(decTb, kIdx, kVal, kc, row, tid, p0, p1, xOut);
        return;
    }

    if (tid == 0) sKeep = nDef;

    // compute phase: chain waves run np-exact band chains; remaining waves
    // compute def-keep values from L2-resident bf16 Encb (fp32 Enc fallback).
    {
        int chainWaves = (Bn + 63) >> 6; if (chainWaves < 1) chainWaves = 1;
        if (wave < chainWaves) {
            if (tid < Bn) bandVal[tid] = np_chain(Enc, benc, xs, bandIdx[tid]);
        } else {
            const int nW = 4 - chainWaves;
            const int wrel = wave - chainWaves;
            float xr[8];
#pragma unroll
            for (int e = 0; e < 8; ++e) xr[e] = xs[lane * 8 + e];
            if (Encb) {
#pragma unroll 2
                for (int j = wrel; j < nDef; j += nW) {
                    int m = defIdx[j];
                    uint4 d = *(const uint4*)(Encb + (size_t)m * H_DIM + lane * 8);
                    float s = xr[0]*bfl(d.x) + xr[1]*bfh(d.x)
                            + xr[2]*bfl(d.y) + xr[3]*bfh(d.y)
                            + xr[4]*bfl(d.z) + xr[5]*bfh(d.z)
                            + xr[6]*bfl(d.w) + xr[7]*bfh(d.w);
#pragma unroll
                    for (int off = 32; off >= 1; off >>= 1) s += __shfl_down(s, off);
                    if (lane == 0) {
                        float lg = s + benc[m];
                        kVal[j] = lg > 0.f ? lg : 0.f;
                        kIdx[j] = m;
                    }
                }
            } else {
                for (int j = wrel; j < nDef; j += nW) {
                    int m = defIdx[j];
                    const float4* er = (const float4*)(Enc + (size_t)m * H_DIM + lane * 8);
                    float4 e0 = er[0], e1 = er[1];
                    float s = xr[0]*e0.x + xr[1]*e0.y + xr[2]*e0.z + xr[3]*e0.w
                            + xr[4]*e1.x + xr[5]*e1.y + xr[6]*e1.z + xr[7]*e1.w;
#pragma unroll
                    for (int off = 32; off >= 1; off >>= 1) s += __shfl_down(s, off);
                    if (lane == 0) {
                        float lg = s + benc[m];
                        kVal[j] = lg > 0.f ? lg : 0.f;
                        kIdx[j] = m;
                    }
                }
            }
        }
    }
    // bulk zero-write, NONTEMPORAL (don't evict decTb/Encb from L2)
    {
        floatx4 z4 = (floatx4){0.f, 0.f, 0.f, 0.f};
        floatx4* dst = (floatx4*)(zbase + (size_t)row * M_DIM);
#pragma unroll
        for (int c = 0; c < 4; ++c)
            __builtin_nontemporal_store(z4, &dst[c * 256 + tid]);
    }
    __syncthreads();   // bandVal/kVal/kIdx ready; zero-writes drained

    // def scatter + band rank/scatter
    if (tid < nDef) zbase[(size_t)row * M_DIM + kIdx[tid]] = kVal[tid];
    if (tid < Bn) {
        float myV = bandVal[tid]; int myM = bandIdx[tid];
        const float eps = 7.2e-8f * myV;    // ~0.6 ulp relative
        int r = 0;
        for (int k = 0; k < Bn; ++k) {
            float v = bandVal[k];
            float d = v - myV;
            bool tie = (d <= eps) && (d >= -eps);
            r += ((!tie && v > myV) || (tie && bandIdx[k] < myM)) ? 1 : 0;
        }
        if (r < (TOPK - nDef)) {
            zbase[(size_t)row * M_DIM + myM] = myV;
            int p = atomicAdd(&sKeep, 1);
            if (p < TOPK) { kIdx[p] = myM; kVal[p] = myV; }
        }
    }
    __syncthreads();
    if (doDec) {
        int kc = sKeep; if (kc > TOPK) kc = TOPK;
        sae_row_decode(decTb, kIdx, kVal, kc, row, tid, p0, p1, xOut);
    }
}

// ---- K3 fallback (only if ws too small for decTb): rescan masked fp32 z row
__launch_bounds__(256, 2)
__global__ void sae_decode_fb(const float* __restrict__ zbase,
                              const float* __restrict__ dec,    // [H, M]
                              const float* __restrict__ bpre,
                              float* __restrict__ xOut)
{
    __shared__ float sVal[4][DEC_CAP];
    __shared__ int   sIdx[4][DEC_CAP];
    __shared__ int   sCnt[4];
    const int lane = threadIdx.x & 63;
    const int wave = threadIdx.x >> 6;
    const int row  = blockIdx.x * 4 + wave;
    if (lane == 0) sCnt[wave] = 0;
    __syncthreads();

    const float* zr = zbase + (size_t)row * M_DIM;
    for (int c = 0; c < 8; ++c) {
        const float4* p4 = (const float4*)(zr + c * 512 + lane * 8);
        float4 t0 = p4[0], t1 = p4[1];
        float tv[8] = {t0.x, t0.y, t0.z, t0.w, t1.x, t1.y, t1.z, t1.w};
#pragma unroll
        for (int e = 0; e < 8; ++e) {
            if (tv[e] != 0.f) {
                int p = atomicAdd(&sCnt[wave], 1);
                if (p < DEC_CAP) { sIdx[wave][p] = c * 512 + lane * 8 + e; sVal[wave][p] = tv[e]; }
            }
        }
    }
    __syncthreads();
    int cnt = sCnt[wave]; if (cnt > DEC_CAP) cnt = DEC_CAP;

    const int hBase = lane * 8;
    float acc[8] = {0.f, 0.f, 0.f, 0.f, 0.f, 0.f, 0.f, 0.f};
    for (int j = 0; j < cnt; ++j) {
        float v = sVal[wave][j];
        int m   = sIdx[wave][j];
#pragma unroll
        for (int e = 0; e < 8; ++e)
            acc[e] += v * dec[(size_t)(hBase + e) * M_DIM + m];
    }
    float4 o0, o1;
    const float* pf = bpre + hBase;
    o0.x = acc[0] + pf[0]; o0.y = acc[1] + pf[1]; o0.z = acc[2] + pf[2]; o0.w = acc[3] + pf[3];
    o1.x = acc[4] + pf[4]; o1.y = acc[5] + pf[5]; o1.z = acc[6] + pf[6]; o1.w = acc[7] + pf[7];
    float* xr = xOut + (size_t)row * H_DIM + hBase;
    ((float4*)xr)[0] = o0; ((float4*)xr)[1] = o1;
}

extern "C" void kernel_launch(void* const* d_in, const int* in_sizes, int n_in,
                              void* d_out, int out_size, void* d_ws, size_t ws_size,
                              hipStream_t stream)
{
    const float* zL   = (const float*)d_in[0]; // [N, H]
    const float* enc  = (const float*)d_in[1]; // [M, H]
    const float* dec  = (const float*)d_in[2]; // [H, M]
    const float* bpre = (const float*)d_in[3]; // [H]
    const float* benc = (const float*)d_in[4]; // [M]
    const int N = in_sizes[0] / H_DIM;         // 16384

    float* zOut = (float*)d_out;               // [N, M]
    float* xOut = zOut + (size_t)N * M_DIM;    // [N, H]
    unsigned short* zb = (unsigned short*)zOut;

    const size_t dectB  = (size_t)M_DIM * H_DIM * 2;   // 4 MB bf16 decT
    const size_t encbB  = (size_t)M_DIM * H_DIM * 2;   // 4 MB bf16 Enc
    const size_t xbfB   = (size_t)N * H_DIM * 2;       // 16 MB bf16 (X - bpre)

    unsigned short *decTb = nullptr, *Encb = nullptr, *Xb = nullptr;
    size_t off = 0;
    if (ws_size >= off + dectB) { decTb = (unsigned short*)((char*)d_ws + off); off += dectB; }
    if (decTb && ws_size >= off + encbB) { Encb = (unsigned short*)((char*)d_ws + off); off += encbB; }
    if (Encb && ws_size >= off + xbfB)   { Xb   = (unsigned short*)((char*)d_ws + off); off += xbfB; }

    if (decTb) sae_conv_decT<<<dim3(M_DIM / 64, H_DIM / 64), 256, 0, stream>>>(dec, decTb);
    if (Encb)  sae_conv_enc<<<(M_DIM * H_DIM) / 2048, 256, 0, stream>>>(enc, Encb);
    if (Xb)    sae_conv_x<<<(int)(((size_t)N * H_DIM) / 2048), 256, 0, stream>>>(zL, bpre, Xb);

    if (Xb) {
        sae_encode_gemm64<<<(M_DIM / 128) * (N / 128), 256, 0, stream>>>(Xb, Encb, benc, zb);
    } else {
        dim3 eg(M_DIM / 128, N / 128);
        if (Encb) sae_encode_gemm<1><<<eg, 256, 0, stream>>>(zL, enc, Encb, bpre, benc, zb);
        else      sae_encode_gemm<0><<<eg, 256, 0, stream>>>(zL, enc, nullptr, bpre, benc, zb);
    }

    sae_topk<<<N, 256, 0, stream>>>(zOut, zL, enc, bpre, benc, decTb, Encb, xOut, decTb ? 1 : 0);
    if (!decTb) sae_decode_fb<<<N / 4, 256, 0, stream>>>(zOut, dec, bpre, xOut);
}

// Round 10
// 809.986 us; speedup vs baseline: 1.1766x; 1.1766x over previous
//
#include <hip/hip_runtime.h>
#include <stdint.h>
#include <stddef.h>

#define H_DIM 512
#define M_DIM 4096
#define TOPK  64
#define BAND_CAP 128
#define DEC_CAP 96
#define NBINS 2048

typedef __attribute__((ext_vector_type(8))) short bf16x8;
typedef __attribute__((ext_vector_type(4))) float floatx4;
typedef __attribute__((ext_vector_type(8))) unsigned short ushort8;

static __device__ __forceinline__ unsigned short f2bf(float f) {
    union { float ff; unsigned int i; } v; v.ff = f;
    unsigned int u = v.i;
    u += 0x7FFFu + ((u >> 16) & 1u);   // RNE
    return (unsigned short)(u >> 16);
}

static __device__ __forceinline__ float bfl(unsigned int u) { return __uint_as_float(u << 16); }
static __device__ __forceinline__ float bfh(unsigned int u) { return __uint_as_float(u & 0xFFFF0000u); }

static __device__ __forceinline__ void gload16(const void* g, void* l) {
    __builtin_amdgcn_global_load_lds(
        (const __attribute__((address_space(1))) unsigned int*)g,
        (__attribute__((address_space(3))) unsigned int*)l, 16, 0, 0);
}

// np-exact fp32 logit: single sequential FMA chain k=0..511 + bias + relu
static __device__ __forceinline__ float np_chain(const float* __restrict__ Enc,
                                                 const float* __restrict__ benc,
                                                 const float* xs, int m) {
    const float* er = Enc + (size_t)m * H_DIM;
    float s = 0.f;
#pragma unroll 8
    for (int k = 0; k < H_DIM; ++k) s = fmaf(xs[k], er[k], s);
    float lg = s + benc[m];
    return lg > 0.f ? lg : 0.f;
}

// ---- prep: Xbf[n*H+h] = bf16(X - bpre)
__global__ void sae_conv_x(const float* __restrict__ X, const float* __restrict__ bpre,
                           unsigned short* __restrict__ Xbf) {
    int g = (blockIdx.x * 256 + threadIdx.x) * 8;
    int h = g & (H_DIM - 1);
    float4 a0 = *(const float4*)(X + g);
    float4 a1 = *(const float4*)(X + g + 4);
    float4 p0 = *(const float4*)(bpre + h);
    float4 p1 = *(const float4*)(bpre + h + 4);
    ushort8 o;
    o[0] = f2bf(a0.x - p0.x); o[1] = f2bf(a0.y - p0.y);
    o[2] = f2bf(a0.z - p0.z); o[3] = f2bf(a0.w - p0.w);
    o[4] = f2bf(a1.x - p1.x); o[5] = f2bf(a1.y - p1.y);
    o[6] = f2bf(a1.z - p1.z); o[7] = f2bf(a1.w - p1.w);
    *(ushort8*)(Xbf + g) = o;
}

// ---- prep: Encbf = bf16(Enc)
__global__ void sae_conv_enc(const float* __restrict__ Enc, unsigned short* __restrict__ Eb) {
    int g = (blockIdx.x * 256 + threadIdx.x) * 8;
    float4 b0 = *(const float4*)(Enc + g);
    float4 b1 = *(const float4*)(Enc + g + 4);
    ushort8 o;
    o[0] = f2bf(b0.x); o[1] = f2bf(b0.y); o[2] = f2bf(b0.z); o[3] = f2bf(b0.w);
    o[4] = f2bf(b1.x); o[5] = f2bf(b1.y); o[6] = f2bf(b1.z); o[7] = f2bf(b1.w);
    *(ushort8*)(Eb + g) = o;
}

// ---- prep: decTb[m*H + h] = bf16(dec[h*M + m])
__global__ void sae_conv_decT(const float* __restrict__ dec, unsigned short* __restrict__ decTb) {
    __shared__ float tile[64][65];
    const int m0 = blockIdx.x * 64;
    const int h0 = blockIdx.y * 64;
    const int tid = threadIdx.x;
#pragma unroll
    for (int it = 0; it < 16; ++it) {
        int r = it * 4 + (tid >> 6);
        int c = tid & 63;
        tile[r][c] = dec[(size_t)(h0 + r) * M_DIM + m0 + c];
    }
    __syncthreads();
    const int ml = tid >> 2;
    const int q  = tid & 3;
    ushort8 o0, o1;
#pragma unroll
    for (int e = 0; e < 8; ++e) o0[e] = f2bf(tile[q * 16 + e][ml]);
#pragma unroll
    for (int e = 0; e < 8; ++e) o1[e] = f2bf(tile[q * 16 + 8 + e][ml]);
    unsigned short* out = decTb + (size_t)(m0 + ml) * H_DIM + h0 + q * 16;
    *(ushort8*)(out)     = o0;
    *(ushort8*)(out + 8) = o1;
}

// ---- K1 fast path (r6-measured config): 128x128 BK=64, 4 blocks/CU,
// plain bf16 epilogue into front half of each fp32 output row slot.
__launch_bounds__(256, 4)
__global__ void sae_encode_gemm64(const unsigned short* __restrict__ Xbf,   // [N,H] bf16
                                  const unsigned short* __restrict__ Encbf, // [M,H] bf16
                                  const float* __restrict__ benc,
                                  unsigned short* __restrict__ zb)
{
    __shared__ unsigned short lA[128 * 64];   // 16 KB
    __shared__ unsigned short lB[128 * 64];   // 16 KB
    const int tid  = threadIdx.x;
    const int lane = tid & 63;
    const int wave = tid >> 6;
    const int wx = wave & 1, wy = wave >> 1;
    const int mBase = blockIdx.x * 128;
    const int nBase = blockIdx.y * 128;

    floatx4 acc[4][4];
#pragma unroll
    for (int i = 0; i < 4; ++i)
#pragma unroll
        for (int j = 0; j < 4; ++j) acc[i][j] = (floatx4){0.f, 0.f, 0.f, 0.f};

    const int gRow = wave * 32 + (lane >> 3);
    const int gCol = (lane & 7) * 8;
    const int lOff = wave * 2048 + lane * 8;
    const unsigned short* gA = Xbf  + (size_t)(nBase + gRow) * H_DIM + gCol;
    const unsigned short* gB = Encbf + (size_t)(mBase + gRow) * H_DIM + gCol;

    const int quad = lane >> 4;
    const int l15  = lane & 15;

    for (int kt = 0; kt < H_DIM / 64; ++kt) {
        const int k0 = kt * 64;
        __syncthreads();
#pragma unroll
        for (int j = 0; j < 4; ++j)
            gload16(gA + (size_t)(j * 8) * H_DIM + k0, &lA[lOff + j * 512]);
#pragma unroll
        for (int j = 0; j < 4; ++j)
            gload16(gB + (size_t)(j * 8) * H_DIM + k0, &lB[lOff + j * 512]);
        __syncthreads();
#pragma unroll
        for (int kk = 0; kk < 2; ++kk) {
            bf16x8 af[4], bfr[4];
#pragma unroll
            for (int i = 0; i < 4; ++i)
                af[i] = *(const bf16x8*)&lA[(wy * 64 + i * 16 + l15) * 64 + kk * 32 + quad * 8];
#pragma unroll
            for (int j = 0; j < 4; ++j)
                bfr[j] = *(const bf16x8*)&lB[(wx * 64 + j * 16 + l15) * 64 + kk * 32 + quad * 8];
#pragma unroll
            for (int i = 0; i < 4; ++i)
#pragma unroll
                for (int j = 0; j < 4; ++j)
                    acc[i][j] = __builtin_amdgcn_mfma_f32_16x16x32_bf16(af[i], bfr[j], acc[i][j], 0, 0, 0);
        }
    }

#pragma unroll
    for (int i = 0; i < 4; ++i) {
        int nLoc = nBase + wy * 64 + i * 16 + quad * 4;
#pragma unroll
        for (int j = 0; j < 4; ++j) {
            int m = mBase + wx * 64 + j * 16 + l15;
            float bc = benc[m];
#pragma unroll
            for (int r = 0; r < 4; ++r) {
                float v = acc[i][j][r] + bc;
                v = v > 0.f ? v : 0.f;
                zb[(size_t)(nLoc + r) * (M_DIM * 2) + m] = f2bf(v);
            }
        }
    }
}

// ---- K1 fallback (small ws): BK=32 128x128 kernel with inline f2bf, bf16 epilogue
template<int BBF>
__launch_bounds__(256, 2)
__global__ void sae_encode_gemm(const float* __restrict__ X,
                                const float* __restrict__ Enc,
                                const unsigned short* __restrict__ Encbf,
                                const float* __restrict__ bpre,
                                const float* __restrict__ benc,
                                unsigned short* __restrict__ zb)
{
    __shared__ unsigned short lA[128 * 32];
    __shared__ unsigned short lB[128 * 32];
    const int tid  = threadIdx.x;
    const int lane = tid & 63;
    const int wave = tid >> 6;
    const int wx = wave & 1, wy = wave >> 1;
    const int mBase = blockIdx.x * 128;
    const int nBase = blockIdx.y * 128;

    floatx4 acc[4][4];
#pragma unroll
    for (int i = 0; i < 4; ++i)
#pragma unroll
        for (int j = 0; j < 4; ++j) acc[i][j] = (floatx4){0.f, 0.f, 0.f, 0.f};

    const int sRow = tid >> 1;
    const int sCol = (tid & 1) * 16;
    const size_t aRow = (size_t)(nBase + sRow) * H_DIM;
    const size_t bRow = (size_t)(mBase + sRow) * H_DIM;
    unsigned short* sA = &lA[sRow * 32 + sCol];
    unsigned short* sB = &lB[sRow * 32 + sCol];

    const int gR0 = wave * 32 + (lane >> 2);
    const int gR1 = gR0 + 16;
    const int gC  = (lane & 3) * 8;
    const int lOff0 = wave * 1024 + lane * 8;
    const int lOff1 = lOff0 + 512;

    const int quad = lane >> 4;
    const int l15  = lane & 15;

    for (int kt = 0; kt < H_DIM / 32; ++kt) {
        const int k0 = kt * 32;
        ushort8 wa0, wa1, wb0, wb1;
#pragma unroll
        for (int c = 0; c < 2; ++c) {
            float4 a0 = *(const float4*)(X + aRow + k0 + sCol + c * 8);
            float4 a1 = *(const float4*)(X + aRow + k0 + sCol + c * 8 + 4);
            float4 p0 = *(const float4*)(bpre + k0 + sCol + c * 8);
            float4 p1 = *(const float4*)(bpre + k0 + sCol + c * 8 + 4);
            ushort8 wa;
            wa[0] = f2bf(a0.x - p0.x); wa[1] = f2bf(a0.y - p0.y);
            wa[2] = f2bf(a0.z - p0.z); wa[3] = f2bf(a0.w - p0.w);
            wa[4] = f2bf(a1.x - p1.x); wa[5] = f2bf(a1.y - p1.y);
            wa[6] = f2bf(a1.z - p1.z); wa[7] = f2bf(a1.w - p1.w);
            if (c == 0) wa0 = wa; else wa1 = wa;
        }
        if constexpr (!BBF) {
#pragma unroll
            for (int c = 0; c < 2; ++c) {
                float4 b0 = *(const float4*)(Enc + bRow + k0 + sCol + c * 8);
                float4 b1 = *(const float4*)(Enc + bRow + k0 + sCol + c * 8 + 4);
                ushort8 wb;
                wb[0] = f2bf(b0.x); wb[1] = f2bf(b0.y); wb[2] = f2bf(b0.z); wb[3] = f2bf(b0.w);
                wb[4] = f2bf(b1.x); wb[5] = f2bf(b1.y); wb[6] = f2bf(b1.z); wb[7] = f2bf(b1.w);
                if (c == 0) wb0 = wb; else wb1 = wb;
            }
        }
        __syncthreads();
        *(ushort8*)(sA)     = wa0;
        *(ushort8*)(sA + 8) = wa1;
        if constexpr (!BBF) {
            *(ushort8*)(sB)     = wb0;
            *(ushort8*)(sB + 8) = wb1;
        } else {
            gload16(Encbf + (size_t)(mBase + gR0) * H_DIM + k0 + gC, &lB[lOff0]);
            gload16(Encbf + (size_t)(mBase + gR1) * H_DIM + k0 + gC, &lB[lOff1]);
        }
        __syncthreads();
        bf16x8 af[4], bfr[4];
#pragma unroll
        for (int i = 0; i < 4; ++i)
            af[i] = *(const bf16x8*)&lA[(wy * 64 + i * 16 + l15) * 32 + quad * 8];
#pragma unroll
        for (int j = 0; j < 4; ++j)
            bfr[j] = *(const bf16x8*)&lB[(wx * 64 + j * 16 + l15) * 32 + quad * 8];
#pragma unroll
        for (int i = 0; i < 4; ++i)
#pragma unroll
            for (int j = 0; j < 4; ++j)
                acc[i][j] = __builtin_amdgcn_mfma_f32_16x16x32_bf16(af[i], bfr[j], acc[i][j], 0, 0, 0);
    }

#pragma unroll
    for (int i = 0; i < 4; ++i) {
        int nLoc = nBase + wy * 64 + i * 16 + quad * 4;
#pragma unroll
        for (int j = 0; j < 4; ++j) {
            int m = mBase + wx * 64 + j * 16 + l15;
            float bc = benc[m];
#pragma unroll
            for (int r = 0; r < 4; ++r) {
                float v = acc[i][j][r] + bc;
                v = v > 0.f ? v : 0.f;
                zb[(size_t)(nLoc + r) * (M_DIM * 2) + m] = f2bf(v);
            }
        }
    }
}

// fused decode: x_tgt row from the kc keeps in LDS, bf16 decT gathers
static __device__ __forceinline__ void sae_row_decode(
    const unsigned short* __restrict__ decTb,
    const int* kIdx, const float* kVal, int kc,
    int row, int tid, float p0, float p1,
    float* __restrict__ xOut)
{
    float a0 = 0.f, a1 = 0.f;
    for (int j = 0; j < kc; ++j) {
        float v = kVal[j];
        int m = kIdx[j];
        unsigned int d = *(const unsigned int*)(decTb + (size_t)m * H_DIM + tid * 2);
        a0 = fmaf(v, bfl(d), a0);
        a1 = fmaf(v, bfh(d), a1);
    }
    float2 o; o.x = a0 + p0; o.y = a1 + p1;
    *(float2*)(xOut + (size_t)row * H_DIM + tid * 2) = o;
}

// ---- K2: exact top-64 from bf16 intermediate (r4 structure).
// Level-1: 2048-bin histogram over the top 12 bf16 bits. Level-2: the low
// 4 bits -> 16-bin pass, giving the EXACT 64th-largest stored bf16 value.
// Def keeps (> hi) keep their stored value (no recompute); band candidates
// get np-exact fp32 chains for ranking. Bulk rewrite + scatter + fused decode.
__launch_bounds__(256, 2)
__global__ void sae_topk(float* __restrict__ zbase,
                         const float* __restrict__ X,
                         const float* __restrict__ Enc,
                         const float* __restrict__ bpre,
                         const float* __restrict__ benc,
                         const unsigned short* __restrict__ decTb,
                         float* __restrict__ xOut,
                         int doDec)
{
    const unsigned short* zb = (const unsigned short*)zbase;
    __shared__ unsigned int hist[NBINS];      // 8 KB
    __shared__ unsigned int h16[16];
    __shared__ unsigned int wsum[4];
    __shared__ unsigned int scanb[256];
    __shared__ float xs[H_DIM];
    __shared__ int   bandIdx[BAND_CAP];
    __shared__ float bandVal[BAND_CAP];
    __shared__ int   kIdx[TOPK];
    __shared__ float kVal[TOPK];
    __shared__ int   sBand, sKeep, sBin, sAbove;

    const int tid  = threadIdx.x;
    const int lane = tid & 63;
    const int wave = tid >> 6;
    const int row  = blockIdx.x;

    // coalesced bf16 row load: elem m(i) = (i>>3)*2048 + tid*8 + (i&7)
    unsigned int u[16];
    float val[16];
    {
        const ushort8* srcb = (const ushort8*)(zb + (size_t)row * (M_DIM * 2));
        ushort8 w0 = srcb[tid];
        ushort8 w1 = srcb[256 + tid];
#pragma unroll
        for (int e = 0; e < 8; ++e) {
            u[e]     = ((unsigned int)(unsigned short)w0[e]) << 16;
            u[8 + e] = ((unsigned int)(unsigned short)w1[e]) << 16;
        }
#pragma unroll
        for (int i = 0; i < 16; ++i) val[i] = __uint_as_float(u[i]);
    }
#define ZIDX(i) (((i) >> 3) * 2048 + tid * 8 + ((i) & 7))

    // early-issue the X row
    float x0 = X[(size_t)row * H_DIM + tid * 2];
    float x1 = X[(size_t)row * H_DIM + tid * 2 + 1];
    float p0 = bpre[tid * 2], p1 = bpre[tid * 2 + 1];

    if (tid == 0) { sBand = 0; sKeep = 0; sBin = -1; }
    if (tid < 16) h16[tid] = 0u;
#pragma unroll
    for (int i = 0; i < NBINS / 256; ++i) hist[tid + i * 256] = 0u;
    __syncthreads();
#pragma unroll
    for (int i = 0; i < 16; ++i)
        if (u[i]) atomicAdd(&hist[u[i] >> 20], 1u);
    __syncthreads();

    // level-1 suffix scan: bin of the 64th-largest + count strictly above
    {
        const int base = tid * 8;
        unsigned int h8[8];
        unsigned int s = 0;
#pragma unroll
        for (int i = 0; i < 8; ++i) { h8[i] = hist[base + i]; s += h8[i]; }
        unsigned int suf = s;
#pragma unroll
        for (int off = 1; off < 64; off <<= 1) {
            unsigned int o = __shfl_down(suf, off);
            if (lane + off < 64) suf += o;
        }
        if (lane == 0) wsum[wave] = suf;
        __syncthreads();
        unsigned int hiW = 0;
        for (int w = wave + 1; w < 4; ++w) hiW += wsum[w];
        suf += hiW;
        if (suf >= (unsigned)TOPK && suf - s < (unsigned)TOPK) {
            unsigned int above = suf - s;
#pragma unroll
            for (int i = 7; i >= 0; --i) {
                if (above + h8[i] >= (unsigned)TOPK) { sBin = base + i; sAbove = (int)above; break; }
                above += h8[i];
            }
        }
        __syncthreads();
    }
    const unsigned int total = wsum[0] + wsum[1] + wsum[2] + wsum[3];

    if (total < (unsigned)TOPK) {
        // fewer than 64 positives: zeros + np-exact keeps (rare path)
        floatx4 z4 = (floatx4){0.f, 0.f, 0.f, 0.f};
        floatx4* dst = (floatx4*)(zbase + (size_t)row * M_DIM);
#pragma unroll
        for (int c = 0; c < 4; ++c) dst[c * 256 + tid] = z4;
        xs[tid * 2]     = x0 - p0;
        xs[tid * 2 + 1] = x1 - p1;
#pragma unroll
        for (int i = 0; i < 16; ++i)
            if (u[i]) {
                int p = atomicAdd(&sKeep, 1);
                if (p < TOPK) kIdx[p] = ZIDX(i);
            }
        __syncthreads();
        int kc = sKeep; if (kc > TOPK) kc = TOPK;
        if (tid < kc) kVal[tid] = np_chain(Enc, benc, xs, kIdx[tid]);
        __syncthreads();
        if (tid < kc) zbase[(size_t)row * M_DIM + kIdx[tid]] = kVal[tid];
        if (doDec) sae_row_decode(decTb, kIdx, kVal, kc, row, tid, p0, p1, xOut);
        return;
    }

    const int b1 = sBin;
    const unsigned int Kneed = (unsigned)TOPK - (unsigned)sAbove;   // >= 1
    __syncthreads();

    // level-2: 16 sub-bins (the low 4 bf16 bits) -> EXACT 64th value
#pragma unroll
    for (int i = 0; i < 16; ++i)
        if (u[i] && (int)(u[i] >> 20) == b1) atomicAdd(&h16[(u[i] >> 16) & 0xFu], 1u);
    __syncthreads();
    int sub = 0;
    {
        unsigned int run = 0;
        for (int i2 = 15; i2 >= 0; --i2) {
            run += h16[i2];
            if (run >= Kneed) { sub = i2; break; }
        }
    }
    const unsigned int T = ((unsigned int)b1 << 20) | ((unsigned int)sub << 16);
    const float Tf  = __uint_as_float(T);              // exact 64th stored value
    const float Tub = __uint_as_float(T + (1u << 16)); // next bf16 up

    // margin: MFMA-vs-np (~0.04+0.01T) + bf16 storage rounding (0.39%)
    const float marg = 0.045f + 0.015f * Tub;
    float lo = Tf - marg; if (lo <= 0.f) lo = 1e-12f;
    const float hi = Tub + marg;

    // collect: def keeps (stored value, straight into decode list) + band; stage xs
#pragma unroll
    for (int i = 0; i < 16; ++i) {
        float v = val[i];
        if (v > hi) {
            int p = atomicAdd(&sKeep, 1);
            if (p < TOPK) { kIdx[p] = ZIDX(i); kVal[p] = v; }
        } else if (v >= lo) {
            int p = atomicAdd(&sBand, 1);
            if (p < BAND_CAP) bandIdx[p] = ZIDX(i);
        }
    }
    xs[tid * 2]     = x0 - p0;
    xs[tid * 2 + 1] = x1 - p1;
    __syncthreads();
    int nDef = sKeep; if (nDef > TOPK) nDef = TOPK;   // mathematically <= 63
    const int Bn = sBand;

    if (Bn > BAND_CAP) {
        // pathological fallback: radix-select on bf16 stored values, np-exact keeps
        if (tid == 0) sKeep = 0;
        floatx4 z4 = (floatx4){0.f, 0.f, 0.f, 0.f};
        floatx4* dst = (floatx4*)(zbase + (size_t)row * M_DIM);
#pragma unroll
        for (int c = 0; c < 4; ++c) dst[c * 256 + tid] = z4;

        unsigned int uold[16];
        {
            const ushort8* so = (const ushort8*)(zb + (size_t)row * (M_DIM * 2)) + tid * 2;
            ushort8 a = so[0], b = so[1];
#pragma unroll
            for (int e = 0; e < 8; ++e) {
                uold[e]     = ((unsigned int)(unsigned short)a[e]) << 16;
                uold[8 + e] = ((unsigned int)(unsigned short)b[e]) << 16;
            }
        }
        unsigned int Tx = 0;
        for (int bit = 30; bit >= 16; --bit) {   // low 16 bits always 0 for bf16
            unsigned int cand = Tx | (1u << bit);
            int c = 0;
#pragma unroll
            for (int i = 0; i < 16; ++i) c += (uold[i] >= cand) ? 1 : 0;
            for (int off = 32; off >= 1; off >>= 1) c += __shfl_down(c, off);
            __syncthreads();
            if (lane == 0) wsum[wave] = (unsigned int)c;
            __syncthreads();
            if (wsum[0] + wsum[1] + wsum[2] + wsum[3] >= TOPK) Tx = cand;
        }
        int c = 0;
#pragma unroll
        for (int i = 0; i < 16; ++i) c += (uold[i] > Tx) ? 1 : 0;
        for (int off = 32; off >= 1; off >>= 1) c += __shfl_down(c, off);
        __syncthreads();
        if (lane == 0) wsum[wave] = (unsigned int)c;
        __syncthreads();
        unsigned int q = TOPK - (wsum[0] + wsum[1] + wsum[2] + wsum[3]);
        unsigned int myT = 0;
#pragma unroll
        for (int i = 0; i < 16; ++i) myT += (uold[i] == Tx) ? 1u : 0u;
        scanb[tid] = myT;
        __syncthreads();
        if (tid == 0) {
            unsigned int run = 0;
            for (int t = 0; t < 256; ++t) { unsigned int c2 = scanb[t]; scanb[t] = run; run += c2; }
        }
        __syncthreads();
        unsigned int tieRank = scanb[tid];
#pragma unroll
        for (int i = 0; i < 16; ++i) {
            bool isTie = (uold[i] == Tx);
            bool keep  = (uold[i] > Tx) || (isTie && tieRank < q);
            if (isTie) tieRank++;
            if (keep) {
                int p = atomicAdd(&sKeep, 1);
                if (p < TOPK) kIdx[p] = tid * 16 + i;
            }
        }
        __syncthreads();
        int kc = sKeep; if (kc > TOPK) kc = TOPK;
        if (tid < kc) kVal[tid] = np_chain(Enc, benc, xs, kIdx[tid]);
        __syncthreads();
        if (tid < kc) zbase[(size_t)row * M_DIM + kIdx[tid]] = kVal[tid];
        if (doDec) sae_row_decode(decTb, kIdx, kVal, kc, row, tid, p0, p1, xOut);
        return;
    }

    // band chains (np-exact ranking); other waves proceed to bulk rewrite
    if (tid < Bn) bandVal[tid] = np_chain(Enc, benc, xs, bandIdx[tid]);

    // bulk rewrite in the row-load layout: def keeps retain stored value, else 0
    {
        float4* dst4 = (float4*)(zbase + (size_t)row * M_DIM);
#pragma unroll
        for (int b = 0; b < 2; ++b)
#pragma unroll
            for (int w = 0; w < 2; ++w) {
                float4 t;
                float v0 = val[b*8 + w*4 + 0], v1 = val[b*8 + w*4 + 1];
                float v2 = val[b*8 + w*4 + 2], v3 = val[b*8 + w*4 + 3];
                t.x = v0 > hi ? v0 : 0.f;
                t.y = v1 > hi ? v1 : 0.f;
                t.z = v2 > hi ? v2 : 0.f;
                t.w = v3 > hi ? v3 : 0.f;
                dst4[b * 512 + tid * 2 + w] = t;
            }
    }
    __syncthreads();   // bandVal ready; bulk writes ordered before band scatter

    // band rank (value desc; ties within 0.6 ulp -> lower index) + scatter
    if (tid < Bn) {
        float myV = bandVal[tid]; int myM = bandIdx[tid];
        const float eps = 7.2e-8f * myV;
        int r = 0;
        for (int k = 0; k < Bn; ++k) {
            float v = bandVal[k];
            float d = v - myV;
            bool tie = (d <= eps) && (d >= -eps);
            r += ((!tie && v > myV) || (tie && bandIdx[k] < myM)) ? 1 : 0;
        }
        if (r < (TOPK - nDef)) {
            zbase[(size_t)row * M_DIM + myM] = myV;
            int p = atomicAdd(&sKeep, 1);
            if (p < TOPK) { kIdx[p] = myM; kVal[p] = myV; }
        }
    }
    __syncthreads();
    if (doDec) {
        int kc = sKeep; if (kc > TOPK) kc = TOPK;
        sae_row_decode(decTb, kIdx, kVal, kc, row, tid, p0, p1, xOut);
    }
}

// ---- K3 fallback (only if ws too small for decTb): rescan masked fp32 z row
__launch_bounds__(256, 2)
__global__ void sae_decode_fb(const float* __restrict__ zbase,
                              const float* __restrict__ dec,    // [H, M]
                              const float* __restrict__ bpre,
                              float* __restrict__ xOut)
{
    __shared__ float sVal[4][DEC_CAP];
    __shared__ int   sIdx[4][DEC_CAP];
    __shared__ int   sCnt[4];
    const int lane = threadIdx.x & 63;
    const int wave = threadIdx.x >> 6;
    const int row  = blockIdx.x * 4 + wave;
    if (lane == 0) sCnt[wave] = 0;
    __syncthreads();

    const float* zr = zbase + (size_t)row * M_DIM;
    for (int c = 0; c < 8; ++c) {
        const float4* p4 = (const float4*)(zr + c * 512 + lane * 8);
        float4 t0 = p4[0], t1 = p4[1];
        float tv[8] = {t0.x, t0.y, t0.z, t0.w, t1.x, t1.y, t1.z, t1.w};
#pragma unroll
        for (int e = 0; e < 8; ++e) {
            if (tv[e] != 0.f) {
                int p = atomicAdd(&sCnt[wave], 1);
                if (p < DEC_CAP) { sIdx[wave][p] = c * 512 + lane * 8 + e; sVal[wave][p] = tv[e]; }
            }
        }
    }
    __syncthreads();
    int cnt = sCnt[wave]; if (cnt > DEC_CAP) cnt = DEC_CAP;

    const int hBase = lane * 8;
    float acc[8] = {0.f, 0.f, 0.f, 0.f, 0.f, 0.f, 0.f, 0.f};
    for (int j = 0; j < cnt; ++j) {
        float v = sVal[wave][j];
        int m   = sIdx[wave][j];
#pragma unroll
        for (int e = 0; e < 8; ++e)
            acc[e] += v * dec[(size_t)(hBase + e) * M_DIM + m];
    }
    float4 o0, o1;
    const float* pf = bpre + hBase;
    o0.x = acc[0] + pf[0]; o0.y = acc[1] + pf[1]; o0.z = acc[2] + pf[2]; o0.w = acc[3] + pf[3];
    o1.x = acc[4] + pf[4]; o1.y = acc[5] + pf[5]; o1.z = acc[6] + pf[6]; o1.w = acc[7] + pf[7];
    float* xr = xOut + (size_t)row * H_DIM + hBase;
    ((float4*)xr)[0] = o0; ((float4*)xr)[1] = o1;
}

extern "C" void kernel_launch(void* const* d_in, const int* in_sizes, int n_in,
                              void* d_out, int out_size, void* d_ws, size_t ws_size,
                              hipStream_t stream)
{
    const float* zL   = (const float*)d_in[0]; // [N, H]
    const float* enc  = (const float*)d_in[1]; // [M, H]
    const float* dec  = (const float*)d_in[2]; // [H, M]
    const float* bpre = (const float*)d_in[3]; // [H]
    const float* benc = (const float*)d_in[4]; // [M]
    const int N = in_sizes[0] / H_DIM;         // 16384

    float* zOut = (float*)d_out;               // [N, M]
    float* xOut = zOut + (size_t)N * M_DIM;    // [N, H]
    unsigned short* zb = (unsigned short*)zOut;

    const size_t dectB  = (size_t)M_DIM * H_DIM * 2;   // 4 MB bf16 decT
    const size_t encbB  = (size_t)M_DIM * H_DIM * 2;   // 4 MB bf16 Enc
    const size_t xbfB   = (size_t)N * H_DIM * 2;       // 16 MB bf16 (X - bpre)

    unsigned short *decTb = nullptr, *Encb = nullptr, *Xb = nullptr;
    size_t off = 0;
    if (ws_size >= off + dectB) { decTb = (unsigned short*)((char*)d_ws + off); off += dectB; }
    if (decTb && ws_size >= off + encbB) { Encb = (unsigned short*)((char*)d_ws + off); off += encbB; }
    if (Encb && ws_size >= off + xbfB)   { Xb   = (unsigned short*)((char*)d_ws + off); off += xbfB; }

    if (decTb) sae_conv_decT<<<dim3(M_DIM / 64, H_DIM / 64), 256, 0, stream>>>(dec, decTb);
    if (Encb)  sae_conv_enc<<<(M_DIM * H_DIM) / 2048, 256, 0, stream>>>(enc, Encb);
    if (Xb)    sae_conv_x<<<(int)(((size_t)N * H_DIM) / 2048), 256, 0, stream>>>(zL, bpre, Xb);

    if (Xb) {
        sae_encode_gemm64<<<dim3(M_DIM / 128, N / 128), 256, 0, stream>>>(Xb, Encb, benc, zb);
    } else {
        dim3 eg(M_DIM / 128, N / 128);
        if (Encb) sae_encode_gemm<1><<<eg, 256, 0, stream>>>(zL, enc, Encb, bpre, benc, zb);
        else      sae_encode_gemm<0><<<eg, 256, 0, stream>>>(zL, enc, nullptr, bpre, benc, zb);
    }

    sae_topk<<<N, 256, 0, stream>>>(zOut, zL, enc, bpre, benc, decTb, xOut, decTb ? 1 : 0);
    if (!decTb) sae_decode_fb<<<N / 4, 256, 0, stream>>>(zOut, dec, bpre, xOut);
}

// Round 11
// 800.392 us; speedup vs baseline: 1.1907x; 1.0120x over previous
//
#include <hip/hip_runtime.h>
#include <stdint.h>
#include <stddef.h>

#define H_DIM 512
#define M_DIM 4096
#define TOPK  64
#define BAND_CAP 128
#define DEC_CAP 96
#define NBINS 2048

typedef __attribute__((ext_vector_type(8))) short bf16x8;
typedef __attribute__((ext_vector_type(4))) float floatx4;
typedef __attribute__((ext_vector_type(8))) unsigned short ushort8;

static __device__ __forceinline__ unsigned short f2bf(float f) {
    union { float ff; unsigned int i; } v; v.ff = f;
    unsigned int u = v.i;
    u += 0x7FFFu + ((u >> 16) & 1u);   // RNE
    return (unsigned short)(u >> 16);
}

static __device__ __forceinline__ float bfl(unsigned int u) { return __uint_as_float(u << 16); }
static __device__ __forceinline__ float bfh(unsigned int u) { return __uint_as_float(u & 0xFFFF0000u); }

static __device__ __forceinline__ void gload16(const void* g, void* l) {
    __builtin_amdgcn_global_load_lds(
        (const __attribute__((address_space(1))) unsigned int*)g,
        (__attribute__((address_space(3))) unsigned int*)l, 16, 0, 0);
}

// np-exact fp32 logit: single sequential FMA chain k=0..511 + bias + relu
static __device__ __forceinline__ float np_chain(const float* __restrict__ Enc,
                                                 const float* __restrict__ benc,
                                                 const float* xs, int m) {
    const float* er = Enc + (size_t)m * H_DIM;
    float s = 0.f;
#pragma unroll 8
    for (int k = 0; k < H_DIM; ++k) s = fmaf(xs[k], er[k], s);
    float lg = s + benc[m];
    return lg > 0.f ? lg : 0.f;
}

// ---- prep: Xbf[n*H+h] = bf16(X - bpre)
__global__ void sae_conv_x(const float* __restrict__ X, const float* __restrict__ bpre,
                           unsigned short* __restrict__ Xbf) {
    int g = (blockIdx.x * 256 + threadIdx.x) * 8;
    int h = g & (H_DIM - 1);
    float4 a0 = *(const float4*)(X + g);
    float4 a1 = *(const float4*)(X + g + 4);
    float4 p0 = *(const float4*)(bpre + h);
    float4 p1 = *(const float4*)(bpre + h + 4);
    ushort8 o;
    o[0] = f2bf(a0.x - p0.x); o[1] = f2bf(a0.y - p0.y);
    o[2] = f2bf(a0.z - p0.z); o[3] = f2bf(a0.w - p0.w);
    o[4] = f2bf(a1.x - p1.x); o[5] = f2bf(a1.y - p1.y);
    o[6] = f2bf(a1.z - p1.z); o[7] = f2bf(a1.w - p1.w);
    *(ushort8*)(Xbf + g) = o;
}

// ---- prep: Encbf = bf16(Enc)
__global__ void sae_conv_enc(const float* __restrict__ Enc, unsigned short* __restrict__ Eb) {
    int g = (blockIdx.x * 256 + threadIdx.x) * 8;
    float4 b0 = *(const float4*)(Enc + g);
    float4 b1 = *(const float4*)(Enc + g + 4);
    ushort8 o;
    o[0] = f2bf(b0.x); o[1] = f2bf(b0.y); o[2] = f2bf(b0.z); o[3] = f2bf(b0.w);
    o[4] = f2bf(b1.x); o[5] = f2bf(b1.y); o[6] = f2bf(b1.z); o[7] = f2bf(b1.w);
    *(ushort8*)(Eb + g) = o;
}

// ---- prep: decTb[m*H + h] = bf16(dec[h*M + m])
__global__ void sae_conv_decT(const float* __restrict__ dec, unsigned short* __restrict__ decTb) {
    __shared__ float tile[64][65];
    const int m0 = blockIdx.x * 64;
    const int h0 = blockIdx.y * 64;
    const int tid = threadIdx.x;
#pragma unroll
    for (int it = 0; it < 16; ++it) {
        int r = it * 4 + (tid >> 6);
        int c = tid & 63;
        tile[r][c] = dec[(size_t)(h0 + r) * M_DIM + m0 + c];
    }
    __syncthreads();
    const int ml = tid >> 2;
    const int q  = tid & 3;
    ushort8 o0, o1;
#pragma unroll
    for (int e = 0; e < 8; ++e) o0[e] = f2bf(tile[q * 16 + e][ml]);
#pragma unroll
    for (int e = 0; e < 8; ++e) o1[e] = f2bf(tile[q * 16 + 8 + e][ml]);
    unsigned short* out = decTb + (size_t)(m0 + ml) * H_DIM + h0 + q * 16;
    *(ushort8*)(out)     = o0;
    *(ushort8*)(out + 8) = o1;
}

// ---- K1 fast path (r6-measured config): 128x128 BK=64, 4 blocks/CU,
// plain bf16 epilogue into front half of each fp32 output row slot.
__launch_bounds__(256, 4)
__global__ void sae_encode_gemm64(const unsigned short* __restrict__ Xbf,   // [N,H] bf16
                                  const unsigned short* __restrict__ Encbf, // [M,H] bf16
                                  const float* __restrict__ benc,
                                  unsigned short* __restrict__ zb)
{
    __shared__ unsigned short lA[128 * 64];   // 16 KB
    __shared__ unsigned short lB[128 * 64];   // 16 KB
    const int tid  = threadIdx.x;
    const int lane = tid & 63;
    const int wave = tid >> 6;
    const int wx = wave & 1, wy = wave >> 1;
    const int mBase = blockIdx.x * 128;
    const int nBase = blockIdx.y * 128;

    floatx4 acc[4][4];
#pragma unroll
    for (int i = 0; i < 4; ++i)
#pragma unroll
        for (int j = 0; j < 4; ++j) acc[i][j] = (floatx4){0.f, 0.f, 0.f, 0.f};

    const int gRow = wave * 32 + (lane >> 3);
    const int gCol = (lane & 7) * 8;
    const int lOff = wave * 2048 + lane * 8;
    const unsigned short* gA = Xbf  + (size_t)(nBase + gRow) * H_DIM + gCol;
    const unsigned short* gB = Encbf + (size_t)(mBase + gRow) * H_DIM + gCol;

    const int quad = lane >> 4;
    const int l15  = lane & 15;

    for (int kt = 0; kt < H_DIM / 64; ++kt) {
        const int k0 = kt * 64;
        __syncthreads();
#pragma unroll
        for (int j = 0; j < 4; ++j)
            gload16(gA + (size_t)(j * 8) * H_DIM + k0, &lA[lOff + j * 512]);
#pragma unroll
        for (int j = 0; j < 4; ++j)
            gload16(gB + (size_t)(j * 8) * H_DIM + k0, &lB[lOff + j * 512]);
        __syncthreads();
#pragma unroll
        for (int kk = 0; kk < 2; ++kk) {
            bf16x8 af[4], bfr[4];
#pragma unroll
            for (int i = 0; i < 4; ++i)
                af[i] = *(const bf16x8*)&lA[(wy * 64 + i * 16 + l15) * 64 + kk * 32 + quad * 8];
#pragma unroll
            for (int j = 0; j < 4; ++j)
                bfr[j] = *(const bf16x8*)&lB[(wx * 64 + j * 16 + l15) * 64 + kk * 32 + quad * 8];
#pragma unroll
            for (int i = 0; i < 4; ++i)
#pragma unroll
                for (int j = 0; j < 4; ++j)
                    acc[i][j] = __builtin_amdgcn_mfma_f32_16x16x32_bf16(af[i], bfr[j], acc[i][j], 0, 0, 0);
        }
    }

#pragma unroll
    for (int i = 0; i < 4; ++i) {
        int nLoc = nBase + wy * 64 + i * 16 + quad * 4;
#pragma unroll
        for (int j = 0; j < 4; ++j) {
            int m = mBase + wx * 64 + j * 16 + l15;
            float bc = benc[m];
#pragma unroll
            for (int r = 0; r < 4; ++r) {
                float v = acc[i][j][r] + bc;
                v = v > 0.f ? v : 0.f;
                zb[(size_t)(nLoc + r) * (M_DIM * 2) + m] = f2bf(v);
            }
        }
    }
}

// ---- K1 fallback (small ws): BK=32 128x128 kernel with inline f2bf, bf16 epilogue
template<int BBF>
__launch_bounds__(256, 2)
__global__ void sae_encode_gemm(const float* __restrict__ X,
                                const float* __restrict__ Enc,
                                const unsigned short* __restrict__ Encbf,
                                const float* __restrict__ bpre,
                                const float* __restrict__ benc,
                                unsigned short* __restrict__ zb)
{
    __shared__ unsigned short lA[128 * 32];
    __shared__ unsigned short lB[128 * 32];
    const int tid  = threadIdx.x;
    const int lane = tid & 63;
    const int wave = tid >> 6;
    const int wx = wave & 1, wy = wave >> 1;
    const int mBase = blockIdx.x * 128;
    const int nBase = blockIdx.y * 128;

    floatx4 acc[4][4];
#pragma unroll
    for (int i = 0; i < 4; ++i)
#pragma unroll
        for (int j = 0; j < 4; ++j) acc[i][j] = (floatx4){0.f, 0.f, 0.f, 0.f};

    const int sRow = tid >> 1;
    const int sCol = (tid & 1) * 16;
    const size_t aRow = (size_t)(nBase + sRow) * H_DIM;
    const size_t bRow = (size_t)(mBase + sRow) * H_DIM;
    unsigned short* sA = &lA[sRow * 32 + sCol];
    unsigned short* sB = &lB[sRow * 32 + sCol];

    const int gR0 = wave * 32 + (lane >> 2);
    const int gR1 = gR0 + 16;
    const int gC  = (lane & 3) * 8;
    const int lOff0 = wave * 1024 + lane * 8;
    const int lOff1 = lOff0 + 512;

    const int quad = lane >> 4;
    const int l15  = lane & 15;

    for (int kt = 0; kt < H_DIM / 32; ++kt) {
        const int k0 = kt * 32;
        ushort8 wa0, wa1, wb0, wb1;
#pragma unroll
        for (int c = 0; c < 2; ++c) {
            float4 a0 = *(const float4*)(X + aRow + k0 + sCol + c * 8);
            float4 a1 = *(const float4*)(X + aRow + k0 + sCol + c * 8 + 4);
            float4 p0 = *(const float4*)(bpre + k0 + sCol + c * 8);
            float4 p1 = *(const float4*)(bpre + k0 + sCol + c * 8 + 4);
            ushort8 wa;
            wa[0] = f2bf(a0.x - p0.x); wa[1] = f2bf(a0.y - p0.y);
            wa[2] = f2bf(a0.z - p0.z); wa[3] = f2bf(a0.w - p0.w);
            wa[4] = f2bf(a1.x - p1.x); wa[5] = f2bf(a1.y - p1.y);
            wa[6] = f2bf(a1.z - p1.z); wa[7] = f2bf(a1.w - p1.w);
            if (c == 0) wa0 = wa; else wa1 = wa;
        }
        if constexpr (!BBF) {
#pragma unroll
            for (int c = 0; c < 2; ++c) {
                float4 b0 = *(const float4*)(Enc + bRow + k0 + sCol + c * 8);
                float4 b1 = *(const float4*)(Enc + bRow + k0 + sCol + c * 8 + 4);
                ushort8 wb;
                wb[0] = f2bf(b0.x); wb[1] = f2bf(b0.y); wb[2] = f2bf(b0.z); wb[3] = f2bf(b0.w);
                wb[4] = f2bf(b1.x); wb[5] = f2bf(b1.y); wb[6] = f2bf(b1.z); wb[7] = f2bf(b1.w);
                if (c == 0) wb0 = wb; else wb1 = wb;
            }
        }
        __syncthreads();
        *(ushort8*)(sA)     = wa0;
        *(ushort8*)(sA + 8) = wa1;
        if constexpr (!BBF) {
            *(ushort8*)(sB)     = wb0;
            *(ushort8*)(sB + 8) = wb1;
        } else {
            gload16(Encbf + (size_t)(mBase + gR0) * H_DIM + k0 + gC, &lB[lOff0]);
            gload16(Encbf + (size_t)(mBase + gR1) * H_DIM + k0 + gC, &lB[lOff1]);
        }
        __syncthreads();
        bf16x8 af[4], bfr[4];
#pragma unroll
        for (int i = 0; i < 4; ++i)
            af[i] = *(const bf16x8*)&lA[(wy * 64 + i * 16 + l15) * 32 + quad * 8];
#pragma unroll
        for (int j = 0; j < 4; ++j)
            bfr[j] = *(const bf16x8*)&lB[(wx * 64 + j * 16 + l15) * 32 + quad * 8];
#pragma unroll
        for (int i = 0; i < 4; ++i)
#pragma unroll
            for (int j = 0; j < 4; ++j)
                acc[i][j] = __builtin_amdgcn_mfma_f32_16x16x32_bf16(af[i], bfr[j], acc[i][j], 0, 0, 0);
    }

#pragma unroll
    for (int i = 0; i < 4; ++i) {
        int nLoc = nBase + wy * 64 + i * 16 + quad * 4;
#pragma unroll
        for (int j = 0; j < 4; ++j) {
            int m = mBase + wx * 64 + j * 16 + l15;
            float bc = benc[m];
#pragma unroll
            for (int r = 0; r < 4; ++r) {
                float v = acc[i][j][r] + bc;
                v = v > 0.f ? v : 0.f;
                zb[(size_t)(nLoc + r) * (M_DIM * 2) + m] = f2bf(v);
            }
        }
    }
}

// fused decode: x_tgt row from the kc keeps in LDS, bf16 decT gathers
static __device__ __forceinline__ void sae_row_decode(
    const unsigned short* __restrict__ decTb,
    const int* kIdx, const float* kVal, int kc,
    int row, int tid, float p0, float p1,
    float* __restrict__ xOut)
{
    float a0 = 0.f, a1 = 0.f;
    for (int j = 0; j < kc; ++j) {
        float v = kVal[j];
        int m = kIdx[j];
        unsigned int d = *(const unsigned int*)(decTb + (size_t)m * H_DIM + tid * 2);
        a0 = fmaf(v, bfl(d), a0);
        a1 = fmaf(v, bfh(d), a1);
    }
    float2 o; o.x = a0 + p0; o.y = a1 + p1;
    *(float2*)(xOut + (size_t)row * H_DIM + tid * 2) = o;
}

// ---- K2: exact top-64 from bf16 intermediate (r10 structure + nt streaming).
// Streaming z IO is NONTEMPORAL (read-once rows, write-once masked output) so
// L3 keeps Enc/decTb/X resident -> band-chain gathers hit L3 instead of HBM.
// Level-2 = 16-bin pass (exact bf16 threshold). Def keeps keep stored values;
// band candidates get np-exact fp32 chains for ranking.
__launch_bounds__(256, 2)
__global__ void sae_topk(float* __restrict__ zbase,
                         const float* __restrict__ X,
                         const float* __restrict__ Enc,
                         const float* __restrict__ bpre,
                         const float* __restrict__ benc,
                         const unsigned short* __restrict__ decTb,
                         float* __restrict__ xOut,
                         int doDec)
{
    const unsigned short* zb = (const unsigned short*)zbase;
    __shared__ unsigned int hist[NBINS];      // 8 KB
    __shared__ unsigned int h16[16];
    __shared__ unsigned int wsum[4];
    __shared__ unsigned int scanb[256];
    __shared__ float xs[H_DIM];
    __shared__ int   bandIdx[BAND_CAP];
    __shared__ float bandVal[BAND_CAP];
    __shared__ int   kIdx[TOPK];
    __shared__ float kVal[TOPK];
    __shared__ int   sBand, sKeep, sBin, sAbove;

    const int tid  = threadIdx.x;
    const int lane = tid & 63;
    const int wave = tid >> 6;
    const int row  = blockIdx.x;

    // coalesced bf16 row load (NONTEMPORAL): elem m(i) = (i>>3)*2048 + tid*8 + (i&7)
    unsigned int u[16];
    float val[16];
    {
        const ushort8* srcb = (const ushort8*)(zb + (size_t)row * (M_DIM * 2));
        ushort8 w0 = __builtin_nontemporal_load(srcb + tid);
        ushort8 w1 = __builtin_nontemporal_load(srcb + 256 + tid);
#pragma unroll
        for (int e = 0; e < 8; ++e) {
            u[e]     = ((unsigned int)(unsigned short)w0[e]) << 16;
            u[8 + e] = ((unsigned int)(unsigned short)w1[e]) << 16;
        }
#pragma unroll
        for (int i = 0; i < 16; ++i) val[i] = __uint_as_float(u[i]);
    }
#define ZIDX(i) (((i) >> 3) * 2048 + tid * 8 + ((i) & 7))

    // early-issue the X row
    float x0 = X[(size_t)row * H_DIM + tid * 2];
    float x1 = X[(size_t)row * H_DIM + tid * 2 + 1];
    float p0 = bpre[tid * 2], p1 = bpre[tid * 2 + 1];

    if (tid == 0) { sBand = 0; sKeep = 0; sBin = -1; }
    if (tid < 16) h16[tid] = 0u;
#pragma unroll
    for (int i = 0; i < NBINS / 256; ++i) hist[tid + i * 256] = 0u;
    __syncthreads();
#pragma unroll
    for (int i = 0; i < 16; ++i)
        if (u[i]) atomicAdd(&hist[u[i] >> 20], 1u);
    __syncthreads();

    // level-1 suffix scan: bin of the 64th-largest + count strictly above
    {
        const int base = tid * 8;
        unsigned int h8[8];
        unsigned int s = 0;
#pragma unroll
        for (int i = 0; i < 8; ++i) { h8[i] = hist[base + i]; s += h8[i]; }
        unsigned int suf = s;
#pragma unroll
        for (int off = 1; off < 64; off <<= 1) {
            unsigned int o = __shfl_down(suf, off);
            if (lane + off < 64) suf += o;
        }
        if (lane == 0) wsum[wave] = suf;
        __syncthreads();
        unsigned int hiW = 0;
        for (int w = wave + 1; w < 4; ++w) hiW += wsum[w];
        suf += hiW;
        if (suf >= (unsigned)TOPK && suf - s < (unsigned)TOPK) {
            unsigned int above = suf - s;
#pragma unroll
            for (int i = 7; i >= 0; --i) {
                if (above + h8[i] >= (unsigned)TOPK) { sBin = base + i; sAbove = (int)above; break; }
                above += h8[i];
            }
        }
        __syncthreads();
    }
    const unsigned int total = wsum[0] + wsum[1] + wsum[2] + wsum[3];

    if (total < (unsigned)TOPK) {
        // fewer than 64 positives: zeros + np-exact keeps (rare path)
        floatx4 z4 = (floatx4){0.f, 0.f, 0.f, 0.f};
        floatx4* dst = (floatx4*)(zbase + (size_t)row * M_DIM);
#pragma unroll
        for (int c = 0; c < 4; ++c)
            __builtin_nontemporal_store(z4, &dst[c * 256 + tid]);
        xs[tid * 2]     = x0 - p0;
        xs[tid * 2 + 1] = x1 - p1;
#pragma unroll
        for (int i = 0; i < 16; ++i)
            if (u[i]) {
                int p = atomicAdd(&sKeep, 1);
                if (p < TOPK) kIdx[p] = ZIDX(i);
            }
        __syncthreads();
        int kc = sKeep; if (kc > TOPK) kc = TOPK;
        if (tid < kc) kVal[tid] = np_chain(Enc, benc, xs, kIdx[tid]);
        __syncthreads();
        if (tid < kc) zbase[(size_t)row * M_DIM + kIdx[tid]] = kVal[tid];
        if (doDec) sae_row_decode(decTb, kIdx, kVal, kc, row, tid, p0, p1, xOut);
        return;
    }

    const int b1 = sBin;
    const unsigned int Kneed = (unsigned)TOPK - (unsigned)sAbove;   // >= 1
    __syncthreads();

    // level-2: 16 sub-bins (the low 4 bf16 bits) -> EXACT 64th value
#pragma unroll
    for (int i = 0; i < 16; ++i)
        if (u[i] && (int)(u[i] >> 20) == b1) atomicAdd(&h16[(u[i] >> 16) & 0xFu], 1u);
    __syncthreads();
    int sub = 0;
    {
        unsigned int run = 0;
        for (int i2 = 15; i2 >= 0; --i2) {
            run += h16[i2];
            if (run >= Kneed) { sub = i2; break; }
        }
    }
    const unsigned int T = ((unsigned int)b1 << 20) | ((unsigned int)sub << 16);
    const float Tf  = __uint_as_float(T);              // exact 64th stored value
    const float Tub = __uint_as_float(T + (1u << 16)); // next bf16 up

    // margin: MFMA-vs-np (validated ~0.04+0.01T, r1-r4) + bf16 storage (<=0.2% T)
    const float marg = 0.042f + 0.0125f * Tub;
    float lo = Tf - marg; if (lo <= 0.f) lo = 1e-12f;
    const float hi = Tub + marg;

    // collect: def keeps (stored value, straight into decode list) + band; stage xs
#pragma unroll
    for (int i = 0; i < 16; ++i) {
        float v = val[i];
        if (v > hi) {
            int p = atomicAdd(&sKeep, 1);
            if (p < TOPK) { kIdx[p] = ZIDX(i); kVal[p] = v; }
        } else if (v >= lo) {
            int p = atomicAdd(&sBand, 1);
            if (p < BAND_CAP) bandIdx[p] = ZIDX(i);
        }
    }
    xs[tid * 2]     = x0 - p0;
    xs[tid * 2 + 1] = x1 - p1;
    __syncthreads();
    int nDef = sKeep; if (nDef > TOPK) nDef = TOPK;   // mathematically <= 63
    const int Bn = sBand;

    if (Bn > BAND_CAP) {
        // pathological fallback: radix-select on bf16 stored values, np-exact keeps
        if (tid == 0) sKeep = 0;
        floatx4 z4 = (floatx4){0.f, 0.f, 0.f, 0.f};
        floatx4* dst = (floatx4*)(zbase + (size_t)row * M_DIM);
#pragma unroll
        for (int c = 0; c < 4; ++c)
            __builtin_nontemporal_store(z4, &dst[c * 256 + tid]);

        unsigned int uold[16];
        {
            const ushort8* so = (const ushort8*)(zb + (size_t)row * (M_DIM * 2)) + tid * 2;
            ushort8 a = so[0], b = so[1];
#pragma unroll
            for (int e = 0; e < 8; ++e) {
                uold[e]     = ((unsigned int)(unsigned short)a[e]) << 16;
                uold[8 + e] = ((unsigned int)(unsigned short)b[e]) << 16;
            }
        }
        unsigned int Tx = 0;
        for (int bit = 30; bit >= 16; --bit) {   // low 16 bits always 0 for bf16
            unsigned int cand = Tx | (1u << bit);
            int c = 0;
#pragma unroll
            for (int i = 0; i < 16; ++i) c += (uold[i] >= cand) ? 1 : 0;
            for (int off = 32; off >= 1; off >>= 1) c += __shfl_down(c, off);
            __syncthreads();
            if (lane == 0) wsum[wave] = (unsigned int)c;
            __syncthreads();
            if (wsum[0] + wsum[1] + wsum[2] + wsum[3] >= TOPK) Tx = cand;
        }
        int c = 0;
#pragma unroll
        for (int i = 0; i < 16; ++i) c += (uold[i] > Tx) ? 1 : 0;
        for (int off = 32; off >= 1; off >>= 1) c += __shfl_down(c, off);
        __syncthreads();
        if (lane == 0) wsum[wave] = (unsigned int)c;
        __syncthreads();
        unsigned int q = TOPK - (wsum[0] + wsum[1] + wsum[2] + wsum[3]);
        unsigned int myT = 0;
#pragma unroll
        for (int i = 0; i < 16; ++i) myT += (uold[i] == Tx) ? 1u : 0u;
        scanb[tid] = myT;
        __syncthreads();
        if (tid == 0) {
            unsigned int run = 0;
            for (int t = 0; t < 256; ++t) { unsigned int c2 = scanb[t]; scanb[t] = run; run += c2; }
        }
        __syncthreads();
        unsigned int tieRank = scanb[tid];
#pragma unroll
        for (int i = 0; i < 16; ++i) {
            bool isTie = (uold[i] == Tx);
            bool keep  = (uold[i] > Tx) || (isTie && tieRank < q);
            if (isTie) tieRank++;
            if (keep) {
                int p = atomicAdd(&sKeep, 1);
                if (p < TOPK) kIdx[p] = tid * 16 + i;
            }
        }
        __syncthreads();
        int kc = sKeep; if (kc > TOPK) kc = TOPK;
        if (tid < kc) kVal[tid] = np_chain(Enc, benc, xs, kIdx[tid]);
        __syncthreads();
        if (tid < kc) zbase[(size_t)row * M_DIM + kIdx[tid]] = kVal[tid];
        if (doDec) sae_row_decode(decTb, kIdx, kVal, kc, row, tid, p0, p1, xOut);
        return;
    }

    // band chains (np-exact ranking); other waves proceed to bulk rewrite
    if (tid < Bn) bandVal[tid] = np_chain(Enc, benc, xs, bandIdx[tid]);

    // bulk rewrite (NONTEMPORAL, row-load layout): def keeps keep stored value, else 0
    {
        floatx4* dst4 = (floatx4*)(zbase + (size_t)row * M_DIM);
#pragma unroll
        for (int b = 0; b < 2; ++b)
#pragma unroll
            for (int w = 0; w < 2; ++w) {
                floatx4 t;
                float v0 = val[b*8 + w*4 + 0], v1 = val[b*8 + w*4 + 1];
                float v2 = val[b*8 + w*4 + 2], v3 = val[b*8 + w*4 + 3];
                t[0] = v0 > hi ? v0 : 0.f;
                t[1] = v1 > hi ? v1 : 0.f;
                t[2] = v2 > hi ? v2 : 0.f;
                t[3] = v3 > hi ? v3 : 0.f;
                __builtin_nontemporal_store(t, &dst4[b * 512 + tid * 2 + w]);
            }
    }
    __syncthreads();   // bandVal ready; bulk writes drained before band scatter

    // band rank (value desc; ties within 0.6 ulp -> lower index) + scatter
    if (tid < Bn) {
        float myV = bandVal[tid]; int myM = bandIdx[tid];
        const float eps = 7.2e-8f * myV;
        int r = 0;
        for (int k = 0; k < Bn; ++k) {
            float v = bandVal[k];
            float d = v - myV;
            bool tie = (d <= eps) && (d >= -eps);
            r += ((!tie && v > myV) || (tie && bandIdx[k] < myM)) ? 1 : 0;
        }
        if (r < (TOPK - nDef)) {
            zbase[(size_t)row * M_DIM + myM] = myV;
            int p = atomicAdd(&sKeep, 1);
            if (p < TOPK) { kIdx[p] = myM; kVal[p] = myV; }
        }
    }
    __syncthreads();
    if (doDec) {
        int kc = sKeep; if (kc > TOPK) kc = TOPK;
        sae_row_decode(decTb, kIdx, kVal, kc, row, tid, p0, p1, xOut);
    }
}

// ---- K3 fallback (only if ws too small for decTb): rescan masked fp32 z row
__launch_bounds__(256, 2)
__global__ void sae_decode_fb(const float* __restrict__ zbase,
                              const float* __restrict__ dec,    // [H, M]
                              const float* __restrict__ bpre,
                              float* __restrict__ xOut)
{
    __shared__ float sVal[4][DEC_CAP];
    __shared__ int   sIdx[4][DEC_CAP];
    __shared__ int   sCnt[4];
    const int lane = threadIdx.x & 63;
    const int wave = threadIdx.x >> 6;
    const int row  = blockIdx.x * 4 + wave;
    if (lane == 0) sCnt[wave] = 0;
    __syncthreads();

    const float* zr = zbase + (size_t)row * M_DIM;
    for (int c = 0; c < 8; ++c) {
        const float4* p4 = (const float4*)(zr + c * 512 + lane * 8);
        float4 t0 = p4[0], t1 = p4[1];
        float tv[8] = {t0.x, t0.y, t0.z, t0.w, t1.x, t1.y, t1.z, t1.w};
#pragma unroll
        for (int e = 0; e < 8; ++e) {
            if (tv[e] != 0.f) {
                int p = atomicAdd(&sCnt[wave], 1);
                if (p < DEC_CAP) { sIdx[wave][p] = c * 512 + lane * 8 + e; sVal[wave][p] = tv[e]; }
            }
        }
    }
    __syncthreads();
    int cnt = sCnt[wave]; if (cnt > DEC_CAP) cnt = DEC_CAP;

    const int hBase = lane * 8;
    float acc[8] = {0.f, 0.f, 0.f, 0.f, 0.f, 0.f, 0.f, 0.f};
    for (int j = 0; j < cnt; ++j) {
        float v = sVal[wave][j];
        int m   = sIdx[wave][j];
#pragma unroll
        for (int e = 0; e < 8; ++e)
            acc[e] += v * dec[(size_t)(hBase + e) * M_DIM + m];
    }
    float4 o0, o1;
    const float* pf = bpre + hBase;
    o0.x = acc[0] + pf[0]; o0.y = acc[1] + pf[1]; o0.z = acc[2] + pf[2]; o0.w = acc[3] + pf[3];
    o1.x = acc[4] + pf[4]; o1.y = acc[5] + pf[5]; o1.z = acc[6] + pf[6]; o1.w = acc[7] + pf[7];
    float* xr = xOut + (size_t)row * H_DIM + hBase;
    ((float4*)xr)[0] = o0; ((float4*)xr)[1] = o1;
}

extern "C" void kernel_launch(void* const* d_in, const int* in_sizes, int n_in,
                              void* d_out, int out_size, void* d_ws, size_t ws_size,
                              hipStream_t stream)
{
    const float* zL   = (const float*)d_in[0]; // [N, H]
    const float* enc  = (const float*)d_in[1]; // [M, H]
    const float* dec  = (const float*)d_in[2]; // [H, M]
    const float* bpre = (const float*)d_in[3]; // [H]
    const float* benc = (const float*)d_in[4]; // [M]
    const int N = in_sizes[0] / H_DIM;         // 16384

    float* zOut = (float*)d_out;               // [N, M]
    float* xOut = zOut + (size_t)N * M_DIM;    // [N, H]
    unsigned short* zb = (unsigned short*)zOut;

    const size_t dectB  = (size_t)M_DIM * H_DIM * 2;   // 4 MB bf16 decT
    const size_t encbB  = (size_t)M_DIM * H_DIM * 2;   // 4 MB bf16 Enc
    const size_t xbfB   = (size_t)N * H_DIM * 2;       // 16 MB bf16 (X - bpre)

    unsigned short *decTb = nullptr, *Encb = nullptr, *Xb = nullptr;
    size_t off = 0;
    if (ws_size >= off + dectB) { decTb = (unsigned short*)((char*)d_ws + off); off += dectB; }
    if (decTb && ws_size >= off + encbB) { Encb = (unsigned short*)((char*)d_ws + off); off += encbB; }
    if (Encb && ws_size >= off + xbfB)   { Xb   = (unsigned short*)((char*)d_ws + off); off += xbfB; }

    if (decTb) sae_conv_decT<<<dim3(M_DIM / 64, H_DIM / 64), 256, 0, stream>>>(dec, decTb);
    if (Encb)  sae_conv_enc<<<(M_DIM * H_DIM) / 2048, 256, 0, stream>>>(enc, Encb);
    if (Xb)    sae_conv_x<<<(int)(((size_t)N * H_DIM) / 2048), 256, 0, stream>>>(zL, bpre, Xb);

    if (Xb) {
        sae_encode_gemm64<<<dim3(M_DIM / 128, N / 128), 256, 0, stream>>>(Xb, Encb, benc, zb);
    } else {
        dim3 eg(M_DIM / 128, N / 128);
        if (Encb) sae_encode_gemm<1><<<eg, 256, 0, stream>>>(zL, enc, Encb, bpre, benc, zb);
        else      sae_encode_gemm<0><<<eg, 256, 0, stream>>>(zL, enc, nullptr, bpre, benc, zb);
    }

    sae_topk<<<N, 256, 0, stream>>>(zOut, zL, enc, bpre, benc, decTb, xOut, decTb ? 1 : 0);
    if (!decTb) sae_decode_fb<<<N / 4, 256, 0, stream>>>(zOut, dec, bpre, xOut);
}